// Round 6
// baseline (111.824 us; speedup 1.0000x reference)
//
#include <hip/hip_runtime.h>
#include <hip/hip_bf16.h>

// Problem sizes (fixed by the reference)
#define S_LEN 256     // sequence length (t)
#define DM    512     // d_model (k / d)
#define DR    512     // d_rnn (s)
#define NC    8       // t-chunks
#define TC    32      // t per chunk (NC*TC == S_LEN)

typedef float f4 __attribute__((ext_vector_type(4)));
typedef float f2 __attribute__((ext_vector_type(2)));

// ws layout (floats):
//   xT  : [512][256]            at 0        (131072)
//   acT : f2[512][256]          at 131072   (262144)
//   hp  : f4[NC][512][128]      at 393216   (2097152)   carries, then h_in (in place)
//   P   : [NC][512]             at 2490368  (4096)

__global__ __launch_bounds__(256) void k_transpose_x(const float* __restrict__ x,
                                                     float* __restrict__ xT) {
    __shared__ float tile[32][33];
    const int k0 = blockIdx.x * 32;
    const int t0 = blockIdx.y * 32;
    const int lx = threadIdx.x & 31;
    const int ly = threadIdx.x >> 5;
#pragma unroll
    for (int i = 0; i < 32; i += 8)
        tile[ly + i][lx] = x[(t0 + ly + i) * DM + k0 + lx];
    __syncthreads();
#pragma unroll
    for (int i = 0; i < 32; i += 8)
        xT[(k0 + ly + i) * S_LEN + t0 + lx] = tile[lx][ly + i];
}

// grid(128): block g -> GEMM rows {4g..4g+3, 512+4g..512+4g+3}; epilogue writes acT.
__global__ __launch_bounds__(256) void k_gemm_act(const float* __restrict__ xT,
                                                  const float* __restrict__ W1,
                                                  const float* __restrict__ b1,
                                                  const float* __restrict__ Lam,
                                                  f2* __restrict__ acT) {
    const int g  = blockIdx.x;       // 0..127
    const int t  = threadIdx.x;      // lane axis = t (coalesced xT loads)
    const int r0 = 4 * g;

    float ai[4] = {0.f, 0.f, 0.f, 0.f};
    float ar[4] = {0.f, 0.f, 0.f, 0.f};
    const float* __restrict__ xb = xT + t;

#pragma unroll 8
    for (int k = 0; k < DM; ++k) {
        const float xv = xb[k * S_LEN];
#pragma unroll
        for (int j = 0; j < 4; ++j) {
            ai[j] = fmaf(xv, W1[(r0 + j) * DM + k], ai[j]);        // wave-uniform
            ar[j] = fmaf(xv, W1[(512 + r0 + j) * DM + k], ar[j]);
        }
    }

#pragma unroll
    for (int j = 0; j < 4; ++j) {
        const float pre_i = ai[j] + b1[r0 + j];
        const float pre_r = ar[j] + b1[512 + r0 + j];
        const float inp = 1.f / (1.f + expf(-pre_i));
        const float rec = 1.f / (1.f + expf(-pre_r));
        const float sp  = log1pf(expf(Lam[r0 + j]));
        const float a   = expf(-8.f * sp * rec);
        const float c   = sqrtf(fmaxf(1.f - a * a, 0.f)) * inp;
        f2 ac; ac.x = a; ac.y = c;
        acT[(r0 + j) * S_LEN + t] = ac;
    }
}

// Shared block geometry for k_carry / k_rec_y:
//   blockIdx.x -> c = bx>>8 (chunk), rem = bx&255, g = rem>>1 (s-group of 4), dh = rem&1
//   thread: sloc = tid>>6 (0..3), dq = tid&63;  s = 4g+sloc, global dq_g = dh*64+dq
//   LDS: x slice [TC][64] f4 (32 KB) + ac [4][TC] f2 — no global loads in t-loop.

__global__ __launch_bounds__(256) void k_carry(const float* __restrict__ x,
                                               const f2* __restrict__ acT,
                                               f4* __restrict__ hp,
                                               float* __restrict__ P) {
    const int bx   = blockIdx.x;
    const int c    = bx >> 8;
    const int rem  = bx & 255;
    const int g    = rem >> 1;
    const int dh   = rem & 1;
    const int tid  = threadIdx.x;
    const int sloc = tid >> 6;
    const int dq   = tid & 63;
    const int s    = g * 4 + sloc;
    const int dqg  = dh * 64 + dq;

    __shared__ f4 x_l[TC][64];
    __shared__ f2 ac_l[4][TC];

    const f4* __restrict__ x4 = reinterpret_cast<const f4*>(x);
#pragma unroll
    for (int i = 0; i < 8; ++i) {
        const int t = (tid >> 6) + 4 * i;
        x_l[t][dq] = x4[(c * TC + t) * 128 + dh * 64 + dq];
    }
    if (tid < 128) {
        const int sl = tid >> 5, tt = tid & 31;
        ac_l[sl][tt] = acT[(g * 4 + sl) * S_LEN + c * TC + tt];
    }
    __syncthreads();

    f4 h = (f4)0.f;
    float p = 1.f;

#pragma unroll
    for (int t = 0; t < TC; ++t) {
        const f4 xv = x_l[t][dq];
        const f2 ac = ac_l[sloc][t];
        const float at = ac.x, ct = ac.y;
        h.x = fmaf(at, h.x, ct * xv.x);
        h.y = fmaf(at, h.y, ct * xv.y);
        h.z = fmaf(at, h.z, ct * xv.z);
        h.w = fmaf(at, h.w, ct * xv.w);
        p *= at;
    }

    hp[(c * DR + s) * 128 + dqg] = h;
    if (dq == 0 && dh == 0) P[c * DR + s] = p;
}

// grid(256): serial combine over chunks. Overwrites hp[c] with h_in[c].
// Also writes the final-state output.
__global__ __launch_bounds__(256) void k_combine(const float* __restrict__ state0,
                                                 f4* __restrict__ hp,
                                                 const float* __restrict__ P,
                                                 f4* __restrict__ out4) {
    const int gg = blockIdx.x * 256 + threadIdx.x;
    const int s  = gg >> 7;
    const int dq = gg & 127;

    const f4* __restrict__ st4 = reinterpret_cast<const f4*>(state0);
    f4 h = st4[s * 128 + dq];

#pragma unroll
    for (int c = 0; c < NC; ++c) {
        const f4 carry = hp[(c * DR + s) * 128 + dq];
        hp[(c * DR + s) * 128 + dq] = h;          // h_in for chunk c
        const float pc = P[c * DR + s];           // wave-uniform
        h.x = fmaf(pc, h.x, carry.x);
        h.y = fmaf(pc, h.y, carry.y);
        h.z = fmaf(pc, h.z, carry.z);
        h.w = fmaf(pc, h.w, carry.w);
    }
    out4[(S_LEN * DR) * 128 + s * 128 + dq] = h;
}

// Streams y: LDS-staged x, pure {ds_read + fma + nt store} loop — stores never
// waited on (x reads are lgkmcnt, stores vmcnt).
__global__ __launch_bounds__(256) void k_rec_y(const float* __restrict__ x,
                                               const f4* __restrict__ hin,
                                               const f2* __restrict__ acT,
                                               f4* __restrict__ out4) {
    const int bx   = blockIdx.x;
    const int c    = bx >> 8;
    const int rem  = bx & 255;
    const int g    = rem >> 1;
    const int dh   = rem & 1;
    const int tid  = threadIdx.x;
    const int sloc = tid >> 6;
    const int dq   = tid & 63;
    const int s    = g * 4 + sloc;
    const int dqg  = dh * 64 + dq;

    __shared__ f4 x_l[TC][64];
    __shared__ f2 ac_l[4][TC];

    const f4* __restrict__ x4 = reinterpret_cast<const f4*>(x);
#pragma unroll
    for (int i = 0; i < 8; ++i) {
        const int t = (tid >> 6) + 4 * i;
        x_l[t][dq] = x4[(c * TC + t) * 128 + dh * 64 + dq];
    }
    if (tid < 128) {
        const int sl = tid >> 5, tt = tid & 31;
        ac_l[sl][tt] = acT[(g * 4 + sl) * S_LEN + c * TC + tt];
    }

    f4 h = hin[(c * DR + s) * 128 + dqg];
    __syncthreads();

#pragma unroll
    for (int t = 0; t < TC; ++t) {
        const f4 xv = x_l[t][dq];
        const f2 ac = ac_l[sloc][t];
        const float at = ac.x, ct = ac.y;
        h.x = fmaf(at, h.x, ct * xv.x);
        h.y = fmaf(at, h.y, ct * xv.y);
        h.z = fmaf(at, h.z, ct * xv.z);
        h.w = fmaf(at, h.w, ct * xv.w);
        __builtin_nontemporal_store(h, &out4[((c * TC + t) * DR + s) * 128 + dqg]);
    }
}

extern "C" void kernel_launch(void* const* d_in, const int* in_sizes, int n_in,
                              void* d_out, int out_size, void* d_ws, size_t ws_size,
                              hipStream_t stream) {
    const float* x      = (const float*)d_in[0];
    const float* state0 = (const float*)d_in[1];
    const float* W1     = (const float*)d_in[2];
    const float* b1     = (const float*)d_in[3];
    const float* Lam    = (const float*)d_in[4];

    float* ws  = (float*)d_ws;
    float* xT  = ws;                          // 131072 floats
    f2*    acT = (f2*)(ws + 131072);          // 131072 f2
    f4*    hp  = (f4*)(ws + 393216);          // NC*512*128 f4
    float* P   = ws + 2490368;                // NC*512 floats

    f4* out4 = (f4*)d_out;

    k_transpose_x<<<dim3(16, 8), 256, 0, stream>>>(x, xT);
    k_gemm_act<<<dim3(128), 256, 0, stream>>>(xT, W1, b1, Lam, acT);
    k_carry<<<dim3(NC * 256), 256, 0, stream>>>(x, acT, hp, P);
    k_combine<<<dim3(256), 256, 0, stream>>>(state0, hp, P, out4);
    k_rec_y<<<dim3(NC * 256), 256, 0, stream>>>(x, hp, acT, out4);
}

// Round 7
// 83.467 us; speedup vs baseline: 1.3397x; 1.3397x over previous
//
#include <hip/hip_runtime.h>
#include <hip/hip_bf16.h>

// Problem sizes (fixed by the reference)
#define S_LEN 256     // sequence length (t)
#define DM    512     // d_model (k / d)
#define DR    512     // d_rnn (s)
#define SECT  8       // t-steps per LDS section
#define NSEC  (S_LEN / SECT)   // 32

typedef float f4 __attribute__((ext_vector_type(4)));
typedef float f2 __attribute__((ext_vector_type(2)));

// ws layout (floats):
//   xT  : [512][256]     at 0       (131072)
//   acT : f2[512][256]   at 131072  (262144)

__global__ __launch_bounds__(256) void k_transpose_x(const float* __restrict__ x,
                                                     float* __restrict__ xT) {
    __shared__ float tile[32][33];
    const int k0 = blockIdx.x * 32;
    const int t0 = blockIdx.y * 32;
    const int lx = threadIdx.x & 31;
    const int ly = threadIdx.x >> 5;
#pragma unroll
    for (int i = 0; i < 32; i += 8)
        tile[ly + i][lx] = x[(t0 + ly + i) * DM + k0 + lx];
    __syncthreads();
#pragma unroll
    for (int i = 0; i < 32; i += 8)
        xT[(k0 + ly + i) * S_LEN + t0 + lx] = tile[lx][ly + i];
}

// grid(128): block g -> GEMM rows {4g..4g+3, 512+4g..512+4g+3}; epilogue writes acT.
__global__ __launch_bounds__(256) void k_gemm_act(const float* __restrict__ xT,
                                                  const float* __restrict__ W1,
                                                  const float* __restrict__ b1,
                                                  const float* __restrict__ Lam,
                                                  f2* __restrict__ acT) {
    const int g  = blockIdx.x;       // 0..127
    const int t  = threadIdx.x;      // lane axis = t (coalesced xT loads)
    const int r0 = 4 * g;

    float ai[4] = {0.f, 0.f, 0.f, 0.f};
    float ar[4] = {0.f, 0.f, 0.f, 0.f};
    const float* __restrict__ xb = xT + t;

#pragma unroll 8
    for (int k = 0; k < DM; ++k) {
        const float xv = xb[k * S_LEN];
#pragma unroll
        for (int j = 0; j < 4; ++j) {
            ai[j] = fmaf(xv, W1[(r0 + j) * DM + k], ai[j]);        // wave-uniform
            ar[j] = fmaf(xv, W1[(512 + r0 + j) * DM + k], ar[j]);
        }
    }

#pragma unroll
    for (int j = 0; j < 4; ++j) {
        const float pre_i = ai[j] + b1[r0 + j];
        const float pre_r = ar[j] + b1[512 + r0 + j];
        const float inp = 1.f / (1.f + expf(-pre_i));
        const float rec = 1.f / (1.f + expf(-pre_r));
        const float sp  = log1pf(expf(Lam[r0 + j]));
        const float a   = expf(-8.f * sp * rec);
        const float c   = sqrtf(fmaxf(1.f - a * a, 0.f)) * inp;
        f2 ac; ac.x = a; ac.y = c;
        acT[(r0 + j) * S_LEN + t] = ac;
    }
}

// grid(256) x 256: block = s-pair, full t sweep. x staged in double-buffered LDS
// sections; section boundary = lgkmcnt(0)+raw s_barrier (NO vmcnt drain), so nt
// stores are only waited via counted vmcnt a full section after issue.
__global__ __launch_bounds__(256) void k_rec(const float* __restrict__ x,
                                             const float* __restrict__ state0,
                                             const f2* __restrict__ acT,
                                             f4* __restrict__ out4) {
    const int bx   = blockIdx.x;         // s-pair
    const int tid  = threadIdx.x;
    const int sloc = tid >> 7;           // 0..1
    const int lane = tid & 63;
    const int dh   = (tid >> 6) & 1;
    const int dq   = dh * 64 + lane;     // 0..127
    const int s    = bx * 2 + sloc;

    __shared__ f4 xbuf[2][SECT][128];    // 32 KB
    __shared__ f2 ac_l[2][S_LEN];        // 4 KB

    const f4* __restrict__ x4  = reinterpret_cast<const f4*>(x);
    const f4* __restrict__ st4 = reinterpret_cast<const f4*>(state0);

    // stage a,c for both s rows (512 f2, 2 per thread)
#pragma unroll
    for (int i = 0; i < 2; ++i) {
        const int idx = i * 256 + tid;
        const int sl = idx >> 8, tt = idx & 255;
        ac_l[sl][tt] = acT[(bx * 2 + sl) * S_LEN + tt];
    }

    f4 h = st4[s * 128 + dq];

    // preload section 0 into registers
    f4 xr[4];
#pragma unroll
    for (int i = 0; i < 4; ++i) {
        const int idx = i * 256 + tid;               // 0..1023
        const int tl = idx >> 7, dql = idx & 127;
        xr[i] = x4[tl * 128 + dql];
    }

    for (int ss = 0; ss < NSEC; ++ss) {
        const int buf = ss & 1;
        // write current section to LDS (compiler inserts counted vmcnt for xr)
#pragma unroll
        for (int i = 0; i < 4; ++i) {
            const int idx = i * 256 + tid;
            const int tl = idx >> 7, dql = idx & 127;
            xbuf[buf][tl][dql] = xr[i];
        }
        asm volatile("s_waitcnt lgkmcnt(0)" ::: "memory");  // release own ds_writes
        __builtin_amdgcn_s_barrier();                       // raw barrier: vmcnt NOT drained

        // issue next section's loads (consumed one section later)
        if (ss + 1 < NSEC) {
#pragma unroll
            for (int i = 0; i < 4; ++i) {
                const int idx = i * 256 + tid;
                const int tl = idx >> 7, dql = idx & 127;
                xr[i] = x4[((ss + 1) * SECT + tl) * 128 + dql];
            }
        }

        const int t0 = ss * SECT;
#pragma unroll
        for (int t = 0; t < SECT; ++t) {
            const f2 ac = ac_l[sloc][t0 + t];        // wave-uniform broadcast
            const f4 xv = xbuf[buf][t][dq];
            h.x = fmaf(ac.x, h.x, ac.y * xv.x);
            h.y = fmaf(ac.x, h.y, ac.y * xv.y);
            h.z = fmaf(ac.x, h.z, ac.y * xv.z);
            h.w = fmaf(ac.x, h.w, ac.y * xv.w);
            __builtin_nontemporal_store(h, &out4[((t0 + t) * DR + s) * 128 + dq]);
        }
    }

    // final state
    out4[(S_LEN * DR) * 128 + s * 128 + dq] = h;
}

extern "C" void kernel_launch(void* const* d_in, const int* in_sizes, int n_in,
                              void* d_out, int out_size, void* d_ws, size_t ws_size,
                              hipStream_t stream) {
    const float* x      = (const float*)d_in[0];
    const float* state0 = (const float*)d_in[1];
    const float* W1     = (const float*)d_in[2];
    const float* b1     = (const float*)d_in[3];
    const float* Lam    = (const float*)d_in[4];

    float* ws  = (float*)d_ws;
    float* xT  = ws;                      // 131072 floats
    f2*    acT = (f2*)(ws + 131072);      // 131072 f2

    f4* out4 = (f4*)d_out;

    k_transpose_x<<<dim3(16, 8), 256, 0, stream>>>(x, xT);
    k_gemm_act<<<dim3(128), 256, 0, stream>>>(xT, W1, b1, Lam, acT);
    k_rec<<<dim3(256), 256, 0, stream>>>(x, state0, acT, out4);
}